// Round 1
// baseline (252.423 us; speedup 1.0000x reference)
//
#include <hip/hip_runtime.h>

typedef unsigned short u16;
typedef __attribute__((ext_vector_type(8))) short bf16x8;
typedef __attribute__((ext_vector_type(4))) float f32x4;

#define B_   128
#define P_   2048
#define NP_  32
#define NC_  10
#define F_   160      // NC*CLO
#define NBLK 256      // pass-kernel blocks
#define PPB  8        // p values per block
#define XS   40       // x_tile row stride in shorts (padded: 2-way-max bank conflicts, 16B aligned rows)
#define WS   40       // w_tile row stride
#define VS   164      // v_lds row stride

__device__ __forceinline__ u16 f2bf(float f) {
    union { float f; unsigned u; } v; v.f = f;
    unsigned r = v.u + 0x7FFFu + ((v.u >> 16) & 1u);   // round-to-nearest-even
    return (u16)(r >> 16);
}
__device__ __forceinline__ float bf2f(u16 h) {
    union { unsigned u; float f; } v; v.u = ((unsigned)h) << 16;
    return v.f;
}

// squash tensor along NP, cast bf16, transpose to xb[p][b][kk]
__global__ void k_squash_x(const float* __restrict__ t, u16* __restrict__ xb) {
    int g = blockIdx.x * 256 + threadIdx.x;      // 0..262143
    int p = g >> 7, b = g & 127;
    const float4* tp = (const float4*)(t + (b * P_ + p) * NP_);
    float4 v[8];
    float ss = 0.f;
#pragma unroll
    for (int i = 0; i < 8; ++i) {
        v[i] = tp[i];
        ss += v[i].x*v[i].x + v[i].y*v[i].y + v[i].z*v[i].z + v[i].w*v[i].w;
    }
    float fct = ss / ((1.f + ss) * sqrtf(ss));
    ushort4* xo = (ushort4*)(xb + (p * 128 + b) * NP_);
#pragma unroll
    for (int i = 0; i < 8; ++i) {
        ushort4 h;
        h.x = f2bf(v[i].x * fct); h.y = f2bf(v[i].y * fct);
        h.z = f2bf(v[i].z * fct); h.w = f2bf(v[i].w * fct);
        xo[i] = h;
    }
}

// weight[p][kk][f] fp32 -> wb[p][f][kk] bf16
__global__ void k_wt(const float* __restrict__ w, u16* __restrict__ wb) {
    __shared__ u16 wl[NP_ * F_];
    int p = blockIdx.x, tid = threadIdx.x;
    const float* wp = w + p * NP_ * F_;
    for (int e = tid; e < NP_ * F_; e += 256) wl[e] = f2bf(wp[e]);
    __syncthreads();
    u16* wo = wb + p * F_ * NP_;
    for (int sid = tid; sid < 640; sid += 256) {
        int f = sid >> 2, k0 = (sid & 3) << 3;
        u16 tmp[8];
#pragma unroll
        for (int j = 0; j < 8; ++j) tmp[j] = wl[(k0 + j) * F_ + f];
        *(uint4*)(wo + f * NP_ + k0) = *(uint4*)tmp;
    }
}

// One routing pass. mode 0: c=0.1 uniform. mode 1: t=u.v0, write bias, softmax(t).
// mode 2: t=u.v1 + bias, softmax. Writes per-block partial s.
__global__ __launch_bounds__(512) void k_pass(
        const u16* __restrict__ xb, const u16* __restrict__ wb,
        const float* __restrict__ vprev, float* __restrict__ bias,
        float* __restrict__ s_part, int mode)
{
    __shared__ u16 xt[128 * XS];
    __shared__ u16 wt[F_ * WS];
    __shared__ u16 vl[128 * VS];
    int tid = threadIdx.x;
    int wv = tid >> 6, L = tid & 63, q = L >> 4, col = L & 15;
    int b = wv * 16 + col;      // this lane's batch row (8 waves x 16 cols = 128)
    int kq = q * 4;             // this lane's k' base (k' = q*4 + r)

    if (mode != 0) {            // stage v_prev (fp32 global) as bf16 into LDS
        const float4* vp4 = (const float4*)vprev;
        for (int i = tid; i < 5120; i += 512) {
            float4 vv = vp4[i];
            int bb = i / 40, part = i % 40;
            ushort4 h;
            h.x = f2bf(vv.x); h.y = f2bf(vv.y); h.z = f2bf(vv.z); h.w = f2bf(vv.w);
            *(ushort4*)&vl[bb * VS + part * 4] = h;
        }
    }

    float s_acc[NC_][4];
#pragma unroll
    for (int n = 0; n < NC_; ++n)
#pragma unroll
        for (int r = 0; r < 4; ++r) s_acc[n][r] = 0.f;

    int p0 = blockIdx.x * PPB;
    for (int pp = 0; pp < PPB; ++pp) {
        int p = p0 + pp;
        __syncthreads();   // previous tile fully consumed (+ v_lds visible on first iter)
        const uint4* xg = (const uint4*)(xb + p * 4096);
        const uint4* wg = (const uint4*)(wb + p * 5120);
        for (int c = tid; c < 1152; c += 512) {
            if (c < 512) {
                int row = c >> 2, part = c & 3;
                *(uint4*)&xt[row * XS + part * 8] = xg[c];
            } else {
                int cc = c - 512, f = cc >> 2, part = cc & 3;
                *(uint4*)&wt[f * WS + part * 8] = wg[cc];
            }
        }
        __syncthreads();

        // D'[f][b] = W'(160x32) . x^T(32x128); this wave: all 10 f-tiles, b-tile = wv
        bf16x8 bfrag = *(const bf16x8*)&xt[b * XS + q * 8];   // B[k=q*8+j][n=col]
        f32x4 acc[NC_];
#pragma unroll
        for (int n = 0; n < NC_; ++n) {
            bf16x8 afrag = *(const bf16x8*)&wt[(n * 16 + col) * WS + q * 8]; // A[m=col][k=q*8+j]
            f32x4 z = {0.f, 0.f, 0.f, 0.f};
            acc[n] = __builtin_amdgcn_mfma_f32_16x16x32_bf16(afrag, bfrag, z, 0, 0, 0);
        }
        // lane holds u[b][n][k'=kq+r] in acc[n][r]

        if (mode == 0) {
#pragma unroll
            for (int n = 0; n < NC_; ++n)
#pragma unroll
                for (int r = 0; r < 4; ++r) s_acc[n][r] += 0.1f * acc[n][r];
        } else {
            float tt[NC_];
#pragma unroll
            for (int n = 0; n < NC_; ++n) {
                ushort4 h = *(const ushort4*)&vl[b * VS + n * 16 + kq];
                float t = acc[n][0] * bf2f(h.x) + acc[n][1] * bf2f(h.y)
                        + acc[n][2] * bf2f(h.z) + acc[n][3] * bf2f(h.w);
                t += __shfl_xor(t, 16);           // reduce over q (k' groups)
                t += __shfl_xor(t, 32);
                if (mode == 1) {
                    if (q == (n & 3)) bias[(p * NC_ + n) * 128 + b] = t;
                } else {
                    t += bias[(p * NC_ + n) * 128 + b];
                }
                tt[n] = t;
            }
            float mx = tt[0];
#pragma unroll
            for (int n = 1; n < NC_; ++n) mx = fmaxf(mx, tt[n]);
            float den = 0.f, e[NC_];
#pragma unroll
            for (int n = 0; n < NC_; ++n) { e[n] = __expf(tt[n] - mx); den += e[n]; }
            float inv = 1.f / den;
#pragma unroll
            for (int n = 0; n < NC_; ++n) {
                float c_ = e[n] * inv;
#pragma unroll
                for (int r = 0; r < 4; ++r) s_acc[n][r] += c_ * acc[n][r];
            }
        }
    }

    float* sp = s_part + blockIdx.x * (B_ * F_);
#pragma unroll
    for (int n = 0; n < NC_; ++n) {
        float4 o4 = make_float4(s_acc[n][0], s_acc[n][1], s_acc[n][2], s_acc[n][3]);
        *(float4*)&sp[b * F_ + n * 16 + kq] = o4;
    }
}

// reduce partial s over NBLK groups, squash along CLO (16 consecutive elements)
__global__ void k_red(const float* __restrict__ s_part, float* __restrict__ vout) {
    int o = blockIdx.x * 256 + threadIdx.x;   // grid 80 -> 20480 outputs
    float a = 0.f;
#pragma unroll 8
    for (int g = 0; g < NBLK; ++g) a += s_part[g * (B_ * F_) + o];
    float sq = a * a;
    sq += __shfl_xor(sq, 1);
    sq += __shfl_xor(sq, 2);
    sq += __shfl_xor(sq, 4);
    sq += __shfl_xor(sq, 8);
    vout[o] = a * sq / ((1.f + sq) * sqrtf(sq));
}

extern "C" void kernel_launch(void* const* d_in, const int* in_sizes, int n_in,
                              void* d_out, int out_size, void* d_ws, size_t ws_size,
                              hipStream_t stream) {
    const float* tensor = (const float*)d_in[0];
    const float* weight = (const float*)d_in[1];
    float* out = (float*)d_out;
    char* ws = (char*)d_ws;

    u16*   xb     = (u16*)(ws);                       // 16,777,216 B
    u16*   wb     = (u16*)(ws + 16777216);            // 20,971,520 B
    float* bias   = (float*)(ws + 37748736);          // 10,485,760 B
    float* s_part = (float*)(ws + 48234496);          // 20,971,520 B
    float* v0     = (float*)(ws + 69206016);          //     81,920 B
    float* v1     = (float*)(ws + 69287936);          //     81,920 B

    k_squash_x<<<1024, 256, 0, stream>>>(tensor, xb);
    k_wt<<<2048, 256, 0, stream>>>(weight, wb);

    k_pass<<<NBLK, 512, 0, stream>>>(xb, wb, nullptr, bias, s_part, 0);
    k_red<<<80, 256, 0, stream>>>(s_part, v0);
    k_pass<<<NBLK, 512, 0, stream>>>(xb, wb, v0, bias, s_part, 1);
    k_red<<<80, 256, 0, stream>>>(s_part, v1);
    k_pass<<<NBLK, 512, 0, stream>>>(xb, wb, v1, bias, s_part, 2);
    k_red<<<80, 256, 0, stream>>>(s_part, out);
}